// Round 1
// baseline (840.762 us; speedup 1.0000x reference)
//
#include <hip/hip_runtime.h>
#include <math.h>

#define B_ 1024
#define H_ 4
#define D_ 128
#define V_ 100000
#define M_ (B_*H_)   // 4096
#define EPS_ 1e-7f
#define LOG2E_ 1.4426950408889634f

#define VT_ 64            // v-tile width
#define NT_ 1563          // ceil(V / 64)
#define YB_ 16            // y-blocks
#define TPB_ 98           // ceil(NT / YB)

typedef unsigned short ushort_t;
typedef __attribute__((ext_vector_type(4))) float f32x4;
typedef __attribute__((ext_vector_type(8))) short bf16x8;

__device__ __forceinline__ ushort_t f2bf(float f) {
    unsigned u = __float_as_uint(f);
    unsigned r = u + 0x7fffu + ((u >> 16) & 1u);   // RNE
    return (ushort_t)(r >> 16);
}

__device__ __forceinline__ void gload_lds16(const void* g, void* l) {
    __builtin_amdgcn_global_load_lds(
        (const __attribute__((address_space(1))) unsigned int*)g,
        (__attribute__((address_space(3))) unsigned int*)l,
        16, 0, 0);
}

// ---------------------------------------------------------------------------
// Kernel A: proj = tanh(inputs @ proj_mat.T) * log2(e) -> bf16 [4096,128]
//           pi = softmax(inputs @ mix_mat.T)
// log2(e) folded into A so GEMM epilogues use bare v_exp_f32 (exp2f).
// ---------------------------------------------------------------------------
__global__ __launch_bounds__(512)
void proj_pi_kernel(const float* __restrict__ inputs, const float* __restrict__ proj_mat,
                    const float* __restrict__ mix_mat, ushort_t* __restrict__ Abf,
                    float* __restrict__ pi)
{
    __shared__ float xin[128];
    __shared__ float mixv[4];
    const int b = blockIdx.x, tid = threadIdx.x;
    if (tid < 128) xin[tid] = inputs[b * 128 + tid];
    __syncthreads();

    const float4* row = (const float4*)(proj_mat + tid * 128);
    float acc = 0.f;
#pragma unroll 8
    for (int k = 0; k < 32; ++k) {
        float4 m4 = row[k];
        acc += m4.x * xin[k*4+0] + m4.y * xin[k*4+1] + m4.z * xin[k*4+2] + m4.w * xin[k*4+3];
    }
    Abf[b * 512 + tid] = f2bf(LOG2E_ * tanhf(acc));

    if (tid < 4) {
        const float4* mrow = (const float4*)(mix_mat + tid * 128);
        float a2 = 0.f;
#pragma unroll 8
        for (int k = 0; k < 32; ++k) {
            float4 m4 = mrow[k];
            a2 += m4.x * xin[k*4+0] + m4.y * xin[k*4+1] + m4.z * xin[k*4+2] + m4.w * xin[k*4+3];
        }
        mixv[tid] = a2;
    }
    __syncthreads();
    if (tid < 4) {
        float m = fmaxf(fmaxf(mixv[0], mixv[1]), fmaxf(mixv[2], mixv[3]));
        float e0 = __expf(mixv[0]-m), e1 = __expf(mixv[1]-m), e2 = __expf(mixv[2]-m), e3 = __expf(mixv[3]-m);
        float s = e0 + e1 + e2 + e3;
        float mye = __expf(mixv[tid]-m);
        pi[b * 4 + tid] = mye / s;
    }
}

// ---------------------------------------------------------------------------
// Kernel B: embeddings fp32 -> bf16
// ---------------------------------------------------------------------------
__global__ __launch_bounds__(256)
void conv_kernel(const float* __restrict__ e, ushort_t* __restrict__ o, int n4)
{
    int i = blockIdx.x * 256 + threadIdx.x;
    if (i < n4) {
        float4 f = ((const float4*)e)[i];
        ushort4 u;
        u.x = f2bf(f.x); u.y = f2bf(f.y); u.z = f2bf(f.z); u.w = f2bf(f.w);
        ((ushort4*)o)[i] = u;
    }
}

// ---------------------------------------------------------------------------
// Staging helpers. LDS slot (r,c) <- global 16B chunk c^(r&7)  (XOR swizzle,
// keeps ds_read_b128 of a column at <=2-way bank aliasing which is free).
// global_load_lds writes lane i at ldsbase + i*16, which matches (r,c) linear
// layout since r = t*16 + tid>>4, c = tid&15.
// ---------------------------------------------------------------------------
__device__ __forceinline__ void stage_a(const ushort_t* __restrict__ Abf, ushort_t* lds_a,
                                        int m0, int tid, int wave)
{
#pragma unroll
    for (int t = 0; t < 8; ++t) {
        int r  = t * 16 + (tid >> 4);      // 0..127
        int c  = tid & 15;
        int cs = c ^ (r & 7);
        unsigned loff = (unsigned)__builtin_amdgcn_readfirstlane(t * 4096 + wave * 1024);
        gload_lds16(Abf + (size_t)(m0 + r) * 128 + cs * 8, (char*)lds_a + loff);
    }
}

__device__ __forceinline__ void stage_e(const ushort_t* __restrict__ Ebf, ushort_t* ldsb,
                                        int v0, int tid, int wave)
{
#pragma unroll
    for (int t = 0; t < 4; ++t) {
        int r  = t * 16 + (tid >> 4);      // 0..63
        int c  = tid & 15;
        int cs = c ^ (r & 7);
        int vrow = v0 + r; if (vrow >= V_) vrow = V_ - 1;
        unsigned loff = (unsigned)__builtin_amdgcn_readfirstlane(t * 4096 + wave * 1024);
        gload_lds16(Ebf + (size_t)vrow * 128 + cs * 8, (char*)ldsb + loff);
    }
}

// ---------------------------------------------------------------------------
// Persistent GEMM. A=[4096,128] bf16 (m=b*4+h), E=[100000,128] bf16.
// Grid (32, 16): block owns m-strip [m0, m0+128) and sweeps ~98 v-tiles of 64.
// A staged once; E double-buffered with global_load_lds prefetch.
// 4 waves, each 64m x 32v (acc[4][2]).
// PASS 1: Z[m] += sum_v exp2(logit')   (register-accumulated across tiles,
//         one butterfly + one atomicAdd per lane per block)
// PASS 2: probs[b,v] = sum_h (pi/Z)[b,h] * exp2(logit')
// ---------------------------------------------------------------------------
template <int PASS>
__global__ __launch_bounds__(256, 2)
void gemm_kernel(const ushort_t* __restrict__ Abf, const ushort_t* __restrict__ Ebf,
                 const float* __restrict__ pi, float* __restrict__ Z,
                 float* __restrict__ probs)
{
    __shared__ ushort_t lds_a[128 * 128];
    __shared__ ushort_t lds_e[2][64 * 128];
    __shared__ float w_lds[128];

    const int tid  = threadIdx.x;
    const int wave = tid >> 6;
    const int lane = tid & 63;
    const int q    = lane >> 4;
    const int r16  = lane & 15;
    const int m0   = blockIdx.x * 128;        // x fastest: 32 m-strips share E tile in L2
    const int wm   = (wave >> 1) * 64;
    const int wn   = (wave & 1) * 32;

    const int t_begin = blockIdx.y * TPB_;
    int t_end = t_begin + TPB_; if (t_end > NT_) t_end = NT_;

    if (PASS == 2 && tid < 128) {
        int gi = m0 + tid;
        w_lds[tid] = pi[gi] / Z[gi];
    }

    stage_a(Abf, lds_a, m0, tid, wave);
    stage_e(Ebf, lds_e[0], t_begin * VT_, tid, wave);
    __syncthreads();

    float wreg[4][4];
    if (PASS == 2) {
#pragma unroll
        for (int mi = 0; mi < 4; ++mi)
#pragma unroll
            for (int j = 0; j < 4; ++j)
                wreg[mi][j] = w_lds[wm + mi * 16 + q * 4 + j];
    }

    float zs[4][4];
    if (PASS == 1) {
#pragma unroll
        for (int mi = 0; mi < 4; ++mi)
#pragma unroll
            for (int h = 0; h < 4; ++h) zs[mi][h] = 0.f;
    }

    int bb = 0;
    for (int vt = t_begin; vt < t_end; ++vt) {
        // issue next-tile prefetch into the alternate buffer (async, drains at barrier)
        if (vt + 1 < t_end)
            stage_e(Ebf, lds_e[bb ^ 1], (vt + 1) * VT_, tid, wave);

        f32x4 acc[4][2];
#pragma unroll
        for (int mi = 0; mi < 4; ++mi)
#pragma unroll
            for (int ni = 0; ni < 2; ++ni) acc[mi][ni] = (f32x4)(0.f);

#pragma unroll
        for (int kk = 0; kk < 4; ++kk) {
            int chunk = kk * 4 + q;
            bf16x8 fa[4], fb[2];
#pragma unroll
            for (int mi = 0; mi < 4; ++mi) {
                int row = wm + mi * 16 + r16;
                int sc  = chunk ^ (row & 7);
                fa[mi] = *(const bf16x8*)&lds_a[row * 128 + sc * 8];
            }
#pragma unroll
            for (int ni = 0; ni < 2; ++ni) {
                int row = wn + ni * 16 + r16;
                int sc  = chunk ^ (row & 7);
                fb[ni] = *(const bf16x8*)&lds_e[bb][row * 128 + sc * 8];
            }
#pragma unroll
            for (int mi = 0; mi < 4; ++mi)
#pragma unroll
                for (int ni = 0; ni < 2; ++ni)
                    acc[mi][ni] = __builtin_amdgcn_mfma_f32_16x16x32_bf16(fa[mi], fb[ni], acc[mi][ni], 0, 0, 0);
        }

        // Barrier BETWEEN compute and epilogue: all LDS reads of lds_e[bb] are
        // retired, so next iteration's prefetch may overwrite it while this
        // wave's (register-only + store) epilogue overlaps other waves' MFMA.
        __syncthreads();

        if (PASS == 1) {
#pragma unroll
            for (int mi = 0; mi < 4; ++mi)
#pragma unroll
                for (int ni = 0; ni < 2; ++ni) {
                    int v = vt * VT_ + wn + ni * 16 + r16;
                    bool ok = (v < V_);
#pragma unroll
                    for (int h = 0; h < 4; ++h) {
                        float e = exp2f(acc[mi][ni][h]);
                        zs[mi][h] += ok ? e : 0.f;
                    }
                }
        } else {
#pragma unroll
            for (int mi = 0; mi < 4; ++mi) {
                int mloc = wm + mi * 16 + q * 4;
                size_t rowoff = (size_t)((m0 + mloc) >> 2) * V_;
#pragma unroll
                for (int ni = 0; ni < 2; ++ni) {
                    int v = vt * VT_ + wn + ni * 16 + r16;
                    if (v < V_) {
                        f32x4 a = acc[mi][ni];
                        float p = wreg[mi][0] * exp2f(a[0]) + wreg[mi][1] * exp2f(a[1])
                                + wreg[mi][2] * exp2f(a[2]) + wreg[mi][3] * exp2f(a[3]);
                        probs[rowoff + v] = p;
                    }
                }
            }
        }
        bb ^= 1;
    }

    if (PASS == 1) {
        // one butterfly + one atomic per lane per block (was: per tile)
#pragma unroll
        for (int msk = 1; msk < 16; msk <<= 1) {
#pragma unroll
            for (int mi = 0; mi < 4; ++mi)
#pragma unroll
                for (int h = 0; h < 4; ++h)
                    zs[mi][h] += __shfl_xor(zs[mi][h], msk, 64);
        }
        int mi = r16 >> 2, h = r16 & 3;
        int midx = m0 + wm + mi * 16 + q * 4 + h;
        atomicAdd(&Z[midx], zs[mi][h]);
    }
}

// ---------------------------------------------------------------------------
// Loss: -mean(log(clip(probs[b,label[b]], 1e-7, 1)))
// ---------------------------------------------------------------------------
__global__ __launch_bounds__(256)
void loss_kernel(const float* __restrict__ probs, const int* __restrict__ label,
                 float* __restrict__ out)
{
    __shared__ float red[256];
    int tid = threadIdx.x;
    float s = 0.f;
    for (int b = tid; b < B_; b += 256) {
        float p = probs[(size_t)b * V_ + label[b]];
        p = fminf(fmaxf(p, EPS_), 1.0f);
        s -= logf(p);
    }
    red[tid] = s;
    __syncthreads();
    for (int st = 128; st > 0; st >>= 1) {
        if (tid < st) red[tid] += red[tid + st];
        __syncthreads();
    }
    if (tid == 0) out[0] = red[0] / (float)B_;
}

// ---------------------------------------------------------------------------
extern "C" void kernel_launch(void* const* d_in, const int* in_sizes, int n_in,
                              void* d_out, int out_size, void* d_ws, size_t ws_size,
                              hipStream_t stream)
{
    const float* inputs   = (const float*)d_in[0];
    const int*   label    = (const int*)d_in[1];
    const float* emb      = (const float*)d_in[2];
    const float* proj_mat = (const float*)d_in[3];
    const float* mix_mat  = (const float*)d_in[4];
    float* out = (float*)d_out;

    char* ws = (char*)d_ws;
    ushort_t* emb_bf = (ushort_t*)ws;                       // 25,600,000 B
    ushort_t* A_bf   = (ushort_t*)(ws + 25600000);          //  1,048,576 B
    float*    pi     = (float*)(ws + 26648576);             //     16,384 B
    float*    Z      = (float*)(ws + 26664960);             //     16,384 B

    conv_kernel<<<12500, 256, 0, stream>>>(emb, emb_bf, 3200000);
    proj_pi_kernel<<<1024, 512, 0, stream>>>(inputs, proj_mat, mix_mat, A_bf, pi);
    hipMemsetAsync(Z, 0, 4096 * sizeof(float), stream);

    dim3 g(32, YB_);
    gemm_kernel<1><<<g, 256, 0, stream>>>(A_bf, emb_bf, nullptr, Z, nullptr);
    gemm_kernel<2><<<g, 256, 0, stream>>>(A_bf, emb_bf, pi, Z, out);

    loss_kernel<<<1, 256, 0, stream>>>(out, label, out + (size_t)B_ * V_);
}

// Round 4
// 758.252 us; speedup vs baseline: 1.1088x; 1.1088x over previous
//
#include <hip/hip_runtime.h>
#include <math.h>

#define B_ 1024
#define H_ 4
#define D_ 128
#define V_ 100000
#define M_ (B_*H_)   // 4096
#define EPS_ 1e-7f
#define LOG2E_ 1.4426950408889634f

#define VT_ 128           // v-tile width (E rows per round)
#define NT_ 782           // ceil(V / 128)
#define YB_ 16            // y-blocks
#define TPB_ 49           // ceil(NT / YB)

typedef unsigned short ushort_t;
typedef __attribute__((ext_vector_type(4))) float f32x4;
typedef __attribute__((ext_vector_type(16))) float f32x16;
typedef __attribute__((ext_vector_type(8))) short bf16x8;

__device__ __forceinline__ ushort_t f2bf(float f) {
    unsigned u = __float_as_uint(f);
    unsigned r = u + 0x7fffu + ((u >> 16) & 1u);   // RNE
    return (ushort_t)(r >> 16);
}

__device__ __forceinline__ void gload_lds16(const void* g, void* l) {
    __builtin_amdgcn_global_load_lds(
        (const __attribute__((address_space(1))) unsigned int*)g,
        (__attribute__((address_space(3))) unsigned int*)l,
        16, 0, 0);
}

// ---------------------------------------------------------------------------
// Kernel A: proj = tanh(inputs @ proj_mat.T) * log2(e) -> bf16 [4096,128]
//           pi = softmax(inputs @ mix_mat.T)
// ---------------------------------------------------------------------------
__global__ __launch_bounds__(512)
void proj_pi_kernel(const float* __restrict__ inputs, const float* __restrict__ proj_mat,
                    const float* __restrict__ mix_mat, ushort_t* __restrict__ Abf,
                    float* __restrict__ pi)
{
    __shared__ float xin[128];
    __shared__ float mixv[4];
    const int b = blockIdx.x, tid = threadIdx.x;
    if (tid < 128) xin[tid] = inputs[b * 128 + tid];
    __syncthreads();

    const float4* row = (const float4*)(proj_mat + tid * 128);
    float acc = 0.f;
#pragma unroll 8
    for (int k = 0; k < 32; ++k) {
        float4 m4 = row[k];
        acc += m4.x * xin[k*4+0] + m4.y * xin[k*4+1] + m4.z * xin[k*4+2] + m4.w * xin[k*4+3];
    }
    Abf[b * 512 + tid] = f2bf(LOG2E_ * tanhf(acc));

    if (tid < 4) {
        const float4* mrow = (const float4*)(mix_mat + tid * 128);
        float a2 = 0.f;
#pragma unroll 8
        for (int k = 0; k < 32; ++k) {
            float4 m4 = mrow[k];
            a2 += m4.x * xin[k*4+0] + m4.y * xin[k*4+1] + m4.z * xin[k*4+2] + m4.w * xin[k*4+3];
        }
        mixv[tid] = a2;
    }
    __syncthreads();
    if (tid < 4) {
        float m = fmaxf(fmaxf(mixv[0], mixv[1]), fmaxf(mixv[2], mixv[3]));
        float e0 = __expf(mixv[0]-m), e1 = __expf(mixv[1]-m), e2 = __expf(mixv[2]-m), e3 = __expf(mixv[3]-m);
        float s = e0 + e1 + e2 + e3;
        float mye = __expf(mixv[tid]-m);
        pi[b * 4 + tid] = mye / s;
    }
}

// ---------------------------------------------------------------------------
// Kernel B: embeddings fp32 -> bf16
// ---------------------------------------------------------------------------
__global__ __launch_bounds__(256)
void conv_kernel(const float* __restrict__ e, ushort_t* __restrict__ o, int n4)
{
    int i = blockIdx.x * 256 + threadIdx.x;
    if (i < n4) {
        float4 f = ((const float4*)e)[i];
        ushort4 u;
        u.x = f2bf(f.x); u.y = f2bf(f.y); u.z = f2bf(f.z); u.w = f2bf(f.w);
        ((ushort4*)o)[i] = u;
    }
}

// ---------------------------------------------------------------------------
// E staging: LDS slot (r,c) <- global 16B chunk c^(r&15). Full 4-bit XOR:
// a 32-row fragment read (32x32 MFMA B-operand) lands on 16 distinct 16B
// slots per 16-row stripe -> <=2-way bank aliasing (free).
// global_load_lds dest = wave-uniform base + lane*16 (linear), which matches
// (r,c) since r = t*16 + tid>>4, c = tid&15.
// ---------------------------------------------------------------------------
__device__ __forceinline__ void stage_e(const ushort_t* __restrict__ Ebf, ushort_t* ldsb,
                                        int v0, int tid, int wave)
{
#pragma unroll
    for (int t = 0; t < 8; ++t) {
        int r  = t * 16 + (tid >> 4);      // 0..127
        int c  = tid & 15;
        int cs = c ^ (r & 15);
        int vrow = v0 + r; if (vrow >= V_) vrow = V_ - 1;
        unsigned loff = (unsigned)__builtin_amdgcn_readfirstlane(t * 4096 + wave * 1024);
        gload_lds16(Ebf + (size_t)vrow * 128 + cs * 8, (char*)ldsb + loff);
    }
}

// ---------------------------------------------------------------------------
// Persistent GEMM, 32x32x16 MFMA, A-in-registers.
// A=[4096,128] bf16 (m=b*4+h), E=[100000,128] bf16.
// Grid (32, 16): block owns m-strip [m0, m0+128), sweeps 49 v-tiles of 128.
// A loaded ONCE into VGPRs (fa[2][8] per wave, 64 VGPR) -> zero A LDS traffic.
// E double-buffered in LDS (2x32KB), one barrier per round.
// 4 waves = 2m x 2n, wave tile 64m x 64n (acc 2x2 f32x16).
// 32x32x16 frag layouts: A/B lane l holds [row=l&31][k=(l>>5)*8+j];
//   C/D: col(v)=l&31, row(m)=(reg&3)+8*(reg>>2)+4*(l>>5)   [HW-verified map]
// PASS 1: Z[m] += sum_v exp2(logit')  (register zs, one reduce+atomic per block)
// PASS 2: probs[b,v] = sum_h (pi/Z)[b,h] * exp2(logit')
// ---------------------------------------------------------------------------
template <int PASS>
__global__ __launch_bounds__(256, 2)
void gemm_kernel(const ushort_t* __restrict__ Abf, const ushort_t* __restrict__ Ebf,
                 const float* __restrict__ pi, float* __restrict__ Z,
                 float* __restrict__ probs)
{
    __shared__ ushort_t lds_e[2][VT_ * 128];   // 2 x 32 KB
    __shared__ float w_lds[128];

    const int tid  = threadIdx.x;
    const int wave = tid >> 6;
    const int lane = tid & 63;
    const int l31  = lane & 31;
    const int hi   = lane >> 5;
    const int m0   = blockIdx.x * 128;    // x fastest: 4 blocks/XCD share each E tile in L2
    const int wm   = (wave >> 1) * 64;
    const int wn   = (wave & 1) * 64;

    const int t_begin = blockIdx.y * TPB_;
    int t_end = t_begin + TPB_; if (t_end > NT_) t_end = NT_;

    if (PASS == 2 && tid < 128) {
        int gi = m0 + tid;
        w_lds[tid] = pi[gi] / Z[gi];
    }

    // ---- A fragments -> registers, once (direct from global; L2-resident) ----
    bf16x8 fa[2][8];
#pragma unroll
    for (int mi = 0; mi < 2; ++mi) {
        const ushort_t* arow = Abf + (size_t)(m0 + wm + mi * 32 + l31) * 128 + hi * 8;
#pragma unroll
        for (int kk = 0; kk < 8; ++kk)
            fa[mi][kk] = *(const bf16x8*)(arow + kk * 16);
    }

    stage_e(Ebf, lds_e[0], t_begin * VT_, tid, wave);
    __syncthreads();

    // pass-2 mixture weights, resident per lane: m = wm+mi*32+8*g+4*hi + j
    f32x4 wq[2][4];
    if (PASS == 2) {
#pragma unroll
        for (int mi = 0; mi < 2; ++mi)
#pragma unroll
            for (int g = 0; g < 4; ++g)
                wq[mi][g] = *(const f32x4*)&w_lds[wm + mi * 32 + g * 8 + hi * 4];
    }

    float zs[2][16];
    if (PASS == 1) {
#pragma unroll
        for (int mi = 0; mi < 2; ++mi)
#pragma unroll
            for (int r = 0; r < 16; ++r) zs[mi][r] = 0.f;
    }

    int bb = 0;
    for (int vt = t_begin; vt < t_end; ++vt) {
        // prefetch next tile into alternate buffer (drains at the barrier below)
        if (vt + 1 < t_end)
            stage_e(Ebf, lds_e[bb ^ 1], (vt + 1) * VT_, tid, wave);

        f32x16 acc[2][2];
#pragma unroll
        for (int mi = 0; mi < 2; ++mi)
#pragma unroll
            for (int ni = 0; ni < 2; ++ni) acc[mi][ni] = (f32x16)(0.f);

#pragma unroll
        for (int kk = 0; kk < 8; ++kk) {
            bf16x8 fb[2];
#pragma unroll
            for (int ni = 0; ni < 2; ++ni) {
                int row = wn + ni * 32 + l31;
                int sc  = (kk * 2 + hi) ^ (row & 15);
                fb[ni] = *(const bf16x8*)&lds_e[bb][row * 128 + sc * 8];
            }
#pragma unroll
            for (int mi = 0; mi < 2; ++mi)
#pragma unroll
                for (int ni = 0; ni < 2; ++ni)
                    acc[mi][ni] = __builtin_amdgcn_mfma_f32_32x32x16_bf16(
                        fa[mi][kk], fb[ni], acc[mi][ni], 0, 0, 0);
        }

        // Barrier between compute and epilogue: lds_e[bb] reads retired (safe to
        // overwrite next round), prefetch vmcnt drained, and the register-only
        // epilogue below overlaps other waves' next-round MFMA.
        __syncthreads();

        const int vbase = vt * VT_ + wn + l31;
        if (PASS == 1) {
            bool ok0 = (vbase < V_), ok1 = (vbase + 32 < V_);
#pragma unroll
            for (int mi = 0; mi < 2; ++mi)
#pragma unroll
                for (int r = 0; r < 16; ++r) {
                    float e0 = ok0 ? exp2f(acc[mi][0][r]) : 0.f;
                    float e1 = ok1 ? exp2f(acc[mi][1][r]) : 0.f;
                    zs[mi][r] += e0 + e1;
                }
        } else {
#pragma unroll
            for (int mi = 0; mi < 2; ++mi)
#pragma unroll
                for (int g = 0; g < 4; ++g) {
                    size_t rowoff = (size_t)((m0 + wm + mi * 32 + g * 8 + hi * 4) >> 2) * V_;
#pragma unroll
                    for (int ni = 0; ni < 2; ++ni) {
                        int v = vbase + ni * 32;
                        if (v < V_) {
                            float p = wq[mi][g].x * exp2f(acc[mi][ni][4*g+0])
                                    + wq[mi][g].y * exp2f(acc[mi][ni][4*g+1])
                                    + wq[mi][g].z * exp2f(acc[mi][ni][4*g+2])
                                    + wq[mi][g].w * exp2f(acc[mi][ni][4*g+3]);
                            probs[rowoff + v] = p;
                        }
                    }
                }
        }
        bb ^= 1;
    }

    if (PASS == 1) {
        // reduce zs over the 32 v-columns (lane bits 0..4), once per block
#pragma unroll
        for (int msk = 1; msk < 32; msk <<= 1)
#pragma unroll
            for (int mi = 0; mi < 2; ++mi)
#pragma unroll
                for (int r = 0; r < 16; ++r)
                    zs[mi][r] += __shfl_xor(zs[mi][r], msk, 64);
        // each 32-lane half now holds identical sums; lane (l31 == mi*16+r)
        // writes its half's m (compile-time indices only -> no scratch)
#pragma unroll
        for (int mi = 0; mi < 2; ++mi)
#pragma unroll
            for (int r = 0; r < 16; ++r) {
                if (l31 == mi * 16 + r) {
                    int m = m0 + wm + mi * 32 + (r & 3) + 8 * (r >> 2) + 4 * hi;
                    atomicAdd(&Z[m], zs[mi][r]);
                }
            }
    }
}

// ---------------------------------------------------------------------------
// Loss: -mean(log(clip(probs[b,label[b]], 1e-7, 1)))
// ---------------------------------------------------------------------------
__global__ __launch_bounds__(256)
void loss_kernel(const float* __restrict__ probs, const int* __restrict__ label,
                 float* __restrict__ out)
{
    __shared__ float red[256];
    int tid = threadIdx.x;
    float s = 0.f;
    for (int b = tid; b < B_; b += 256) {
        float p = probs[(size_t)b * V_ + label[b]];
        p = fminf(fmaxf(p, EPS_), 1.0f);
        s -= logf(p);
    }
    red[tid] = s;
    __syncthreads();
    for (int st = 128; st > 0; st >>= 1) {
        if (tid < st) red[tid] += red[tid + st];
        __syncthreads();
    }
    if (tid == 0) out[0] = red[0] / (float)B_;
}

// ---------------------------------------------------------------------------
extern "C" void kernel_launch(void* const* d_in, const int* in_sizes, int n_in,
                              void* d_out, int out_size, void* d_ws, size_t ws_size,
                              hipStream_t stream)
{
    const float* inputs   = (const float*)d_in[0];
    const int*   label    = (const int*)d_in[1];
    const float* emb      = (const float*)d_in[2];
    const float* proj_mat = (const float*)d_in[3];
    const float* mix_mat  = (const float*)d_in[4];
    float* out = (float*)d_out;

    char* ws = (char*)d_ws;
    ushort_t* emb_bf = (ushort_t*)ws;                       // 25,600,000 B
    ushort_t* A_bf   = (ushort_t*)(ws + 25600000);          //  1,048,576 B
    float*    pi     = (float*)(ws + 26648576);             //     16,384 B
    float*    Z      = (float*)(ws + 26664960);             //     16,384 B

    conv_kernel<<<12500, 256, 0, stream>>>(emb, emb_bf, 3200000);
    proj_pi_kernel<<<1024, 512, 0, stream>>>(inputs, proj_mat, mix_mat, A_bf, pi);
    hipMemsetAsync(Z, 0, 4096 * sizeof(float), stream);

    dim3 g(32, YB_);
    gemm_kernel<1><<<g, 256, 0, stream>>>(A_bf, emb_bf, nullptr, Z, nullptr);
    gemm_kernel<2><<<g, 256, 0, stream>>>(A_bf, emb_bf, pi, Z, out);

    loss_kernel<<<1, 256, 0, stream>>>(out, label, out + (size_t)B_ * V_);
}

// Round 5
// 742.578 us; speedup vs baseline: 1.1322x; 1.0211x over previous
//
#include <hip/hip_runtime.h>
#include <math.h>

#define B_ 1024
#define H_ 4
#define D_ 128
#define V_ 100000
#define M_ (B_*H_)   // 4096
#define EPS_ 1e-7f
#define LOG2E_ 1.4426950408889634f

#define VT_ 128           // v-tile width (E rows per round)
#define NT_ 782           // ceil(V / 128)
#define YB_ 16            // y-blocks
#define TPB_ 49           // ceil(NT / YB)

typedef unsigned short ushort_t;
typedef __attribute__((ext_vector_type(4))) float f32x4;
typedef __attribute__((ext_vector_type(16))) float f32x16;
typedef __attribute__((ext_vector_type(8))) short bf16x8;

__device__ __forceinline__ ushort_t f2bf(float f) {
    unsigned u = __float_as_uint(f);
    unsigned r = u + 0x7fffu + ((u >> 16) & 1u);   // RNE
    return (ushort_t)(r >> 16);
}

__device__ __forceinline__ void gload_lds16(const void* g, void* l) {
    __builtin_amdgcn_global_load_lds(
        (const __attribute__((address_space(1))) unsigned int*)g,
        (__attribute__((address_space(3))) unsigned int*)l,
        16, 0, 0);
}

// ---------------------------------------------------------------------------
// Kernel A: proj = tanh(inputs @ proj_mat.T) * log2(e) -> bf16 [4096,128]
//           pi = softmax(inputs @ mix_mat.T)
// ---------------------------------------------------------------------------
__global__ __launch_bounds__(512)
void proj_pi_kernel(const float* __restrict__ inputs, const float* __restrict__ proj_mat,
                    const float* __restrict__ mix_mat, ushort_t* __restrict__ Abf,
                    float* __restrict__ pi)
{
    __shared__ float xin[128];
    __shared__ float mixv[4];
    const int b = blockIdx.x, tid = threadIdx.x;
    if (tid < 128) xin[tid] = inputs[b * 128 + tid];
    __syncthreads();

    const float4* row = (const float4*)(proj_mat + tid * 128);
    float acc = 0.f;
#pragma unroll 8
    for (int k = 0; k < 32; ++k) {
        float4 m4 = row[k];
        acc += m4.x * xin[k*4+0] + m4.y * xin[k*4+1] + m4.z * xin[k*4+2] + m4.w * xin[k*4+3];
    }
    Abf[b * 512 + tid] = f2bf(LOG2E_ * tanhf(acc));

    if (tid < 4) {
        const float4* mrow = (const float4*)(mix_mat + tid * 128);
        float a2 = 0.f;
#pragma unroll 8
        for (int k = 0; k < 32; ++k) {
            float4 m4 = mrow[k];
            a2 += m4.x * xin[k*4+0] + m4.y * xin[k*4+1] + m4.z * xin[k*4+2] + m4.w * xin[k*4+3];
        }
        mixv[tid] = a2;
    }
    __syncthreads();
    if (tid < 4) {
        float m = fmaxf(fmaxf(mixv[0], mixv[1]), fmaxf(mixv[2], mixv[3]));
        float e0 = __expf(mixv[0]-m), e1 = __expf(mixv[1]-m), e2 = __expf(mixv[2]-m), e3 = __expf(mixv[3]-m);
        float s = e0 + e1 + e2 + e3;
        float mye = __expf(mixv[tid]-m);
        pi[b * 4 + tid] = mye / s;
    }
}

// ---------------------------------------------------------------------------
// Kernel B: embeddings fp32 -> bf16
// ---------------------------------------------------------------------------
__global__ __launch_bounds__(256)
void conv_kernel(const float* __restrict__ e, ushort_t* __restrict__ o, int n4)
{
    int i = blockIdx.x * 256 + threadIdx.x;
    if (i < n4) {
        float4 f = ((const float4*)e)[i];
        ushort4 u;
        u.x = f2bf(f.x); u.y = f2bf(f.y); u.z = f2bf(f.z); u.w = f2bf(f.w);
        ((ushort4*)o)[i] = u;
    }
}

// ---------------------------------------------------------------------------
// Persistent GEMM, 32x32x16 MFMA, A-in-registers, STATIC double-buffered E.
// Two distinct __shared__ arrays + unroll-by-2 loop: the compiler can prove
// the in-flight global_load_lds (-> other buffer) doesn't alias the ds_reads
// (-> current buffer), so NO s_waitcnt vmcnt(0) before the MFMA phase; the
// prefetch drains only at the __syncthreads() where it's first needed.
// (Runtime-indexed lds_e[bb] defeated alias analysis and serialized staging.)
//
// E staging: LDS slot (r,c) <- global 16B chunk c^(r&15); fragment read
// inverts it. global_load_lds dest is linear (base + lane*16) which matches
// (r,c) since r = t*16 + tid>>4, c = tid&15.
//
// Grid (32, 16): block owns m-strip [m0,m0+128), sweeps 49 v-tiles of 128.
// 4 waves = 2m x 2n, wave tile 64m x 64n (4 named f32x16 accumulators).
// 32x32x16 frag layouts: A/B lane l holds [row=l&31][k=(l>>5)*8+j];
//   C/D: col(v)=l&31, row(m)=(reg&3)+8*(reg>>2)+4*(l>>5)   [HW-verified map]
// PASS 1: Z[m] += sum_v exp2(logit')  (register zs, one reduce+atomic per block)
// PASS 2: probs[b,v] = sum_h (pi/Z)[b,h] * exp2(logit')
// ---------------------------------------------------------------------------

#define STAGE_E(dst, v0v)                                                     \
    do {                                                                      \
        int v0_ = (v0v);                                                      \
        _Pragma("unroll")                                                     \
        for (int t = 0; t < 8; ++t) {                                         \
            int r_  = t * 16 + (tid >> 4);                                    \
            int c_  = tid & 15;                                               \
            int cs_ = c_ ^ (r_ & 15);                                         \
            int vr_ = v0_ + r_; if (vr_ >= V_) vr_ = V_ - 1;                  \
            unsigned loff_ = (unsigned)__builtin_amdgcn_readfirstlane(        \
                t * 4096 + wave * 1024);                                      \
            gload_lds16(Ebf + (size_t)vr_ * 128 + cs_ * 8,                    \
                        (char*)(dst) + loff_);                                \
        }                                                                     \
    } while (0)

#define ZACC                                                                  \
    do { acc00 = (f32x16)(0.f); acc01 = (f32x16)(0.f);                        \
         acc10 = (f32x16)(0.f); acc11 = (f32x16)(0.f); } while (0)

#define COMPUTE(src)                                                          \
    do {                                                                      \
        _Pragma("unroll")                                                     \
        for (int kk = 0; kk < 8; ++kk) {                                      \
            bf16x8 fb0, fb1;                                                  \
            { int row_ = wn + l31;      int sc_ = (kk*2+hi) ^ (row_ & 15);    \
              fb0 = *(const bf16x8*)&(src)[row_ * 128 + sc_ * 8]; }           \
            { int row_ = wn + 32 + l31; int sc_ = (kk*2+hi) ^ (row_ & 15);    \
              fb1 = *(const bf16x8*)&(src)[row_ * 128 + sc_ * 8]; }           \
            acc00 = __builtin_amdgcn_mfma_f32_32x32x16_bf16(fa[0][kk], fb0, acc00, 0,0,0); \
            acc10 = __builtin_amdgcn_mfma_f32_32x32x16_bf16(fa[1][kk], fb0, acc10, 0,0,0); \
            acc01 = __builtin_amdgcn_mfma_f32_32x32x16_bf16(fa[0][kk], fb1, acc01, 0,0,0); \
            acc11 = __builtin_amdgcn_mfma_f32_32x32x16_bf16(fa[1][kk], fb1, acc11, 0,0,0); \
        }                                                                     \
    } while (0)

#define EPILOGUE(vtv)                                                         \
    do {                                                                      \
        int vbase_ = (vtv) * VT_ + wn + l31;                                  \
        if (PASS == 1) {                                                      \
            bool ok0_ = (vbase_ < V_), ok1_ = (vbase_ + 32 < V_);             \
            _Pragma("unroll")                                                 \
            for (int r = 0; r < 16; ++r) {                                    \
                zs0[r] += (ok0_ ? exp2f(acc00[r]) : 0.f)                      \
                        + (ok1_ ? exp2f(acc01[r]) : 0.f);                     \
                zs1[r] += (ok0_ ? exp2f(acc10[r]) : 0.f)                      \
                        + (ok1_ ? exp2f(acc11[r]) : 0.f);                     \
            }                                                                 \
        } else {                                                              \
            _Pragma("unroll")                                                 \
            for (int g = 0; g < 4; ++g) {                                     \
                size_t ro0_ = (size_t)((m0 + wm +      g*8 + hi*4) >> 2) * V_;\
                size_t ro1_ = (size_t)((m0 + wm + 32 + g*8 + hi*4) >> 2) * V_;\
                if (vbase_ < V_) {                                            \
                    probs[ro0_ + vbase_] =                                    \
                          wq[0][g].x * exp2f(acc00[4*g+0])                    \
                        + wq[0][g].y * exp2f(acc00[4*g+1])                    \
                        + wq[0][g].z * exp2f(acc00[4*g+2])                    \
                        + wq[0][g].w * exp2f(acc00[4*g+3]);                   \
                    probs[ro1_ + vbase_] =                                    \
                          wq[1][g].x * exp2f(acc10[4*g+0])                    \
                        + wq[1][g].y * exp2f(acc10[4*g+1])                    \
                        + wq[1][g].z * exp2f(acc10[4*g+2])                    \
                        + wq[1][g].w * exp2f(acc10[4*g+3]);                   \
                }                                                             \
                if (vbase_ + 32 < V_) {                                       \
                    probs[ro0_ + vbase_ + 32] =                               \
                          wq[0][g].x * exp2f(acc01[4*g+0])                    \
                        + wq[0][g].y * exp2f(acc01[4*g+1])                    \
                        + wq[0][g].z * exp2f(acc01[4*g+2])                    \
                        + wq[0][g].w * exp2f(acc01[4*g+3]);                   \
                    probs[ro1_ + vbase_ + 32] =                               \
                          wq[1][g].x * exp2f(acc11[4*g+0])                    \
                        + wq[1][g].y * exp2f(acc11[4*g+1])                    \
                        + wq[1][g].z * exp2f(acc11[4*g+2])                    \
                        + wq[1][g].w * exp2f(acc11[4*g+3]);                   \
                }                                                             \
            }                                                                 \
        }                                                                     \
    } while (0)

template <int PASS>
__global__ __launch_bounds__(256, 2)
void gemm_kernel(const ushort_t* __restrict__ Abf, const ushort_t* __restrict__ Ebf,
                 const float* __restrict__ pi, float* __restrict__ Z,
                 float* __restrict__ probs)
{
    __shared__ ushort_t lds_e0[VT_ * 128];   // 32 KB
    __shared__ ushort_t lds_e1[VT_ * 128];   // 32 KB
    __shared__ float w_lds[128];

    const int tid  = threadIdx.x;
    const int wave = tid >> 6;
    const int lane = tid & 63;
    const int l31  = lane & 31;
    const int hi   = lane >> 5;
    const int m0   = blockIdx.x * 128;    // x fastest: 4 blocks/XCD share each E tile in L2
    const int wm   = (wave >> 1) * 64;
    const int wn   = (wave & 1) * 64;

    const int t_begin = blockIdx.y * TPB_;
    int t_end = t_begin + TPB_; if (t_end > NT_) t_end = NT_;

    if (PASS == 2 && tid < 128) {
        int gi = m0 + tid;
        w_lds[tid] = pi[gi] / Z[gi];
    }

    // ---- A fragments -> registers, once (direct from global; L2-resident) ----
    bf16x8 fa[2][8];
#pragma unroll
    for (int mi = 0; mi < 2; ++mi) {
        const ushort_t* arow = Abf + (size_t)(m0 + wm + mi * 32 + l31) * 128 + hi * 8;
#pragma unroll
        for (int kk = 0; kk < 8; ++kk)
            fa[mi][kk] = *(const bf16x8*)(arow + kk * 16);
    }

    STAGE_E(lds_e0, t_begin * VT_);
    __syncthreads();

    // pass-2 mixture weights, resident per lane: m = wm+mi*32+8*g+4*hi + j
    f32x4 wq[2][4];
    if (PASS == 2) {
#pragma unroll
        for (int mi = 0; mi < 2; ++mi)
#pragma unroll
            for (int g = 0; g < 4; ++g)
                wq[mi][g] = *(const f32x4*)&w_lds[wm + mi * 32 + g * 8 + hi * 4];
    }

    float zs0[16], zs1[16];
    if (PASS == 1) {
#pragma unroll
        for (int r = 0; r < 16; ++r) { zs0[r] = 0.f; zs1[r] = 0.f; }
    }

    f32x16 acc00, acc01, acc10, acc11;

    int vt = t_begin;
    for (;;) {
        // --- round A: compute from e0, prefetch into e1 (provably no alias) ---
        if (vt + 1 < t_end) STAGE_E(lds_e1, (vt + 1) * VT_);
        ZACC;
        COMPUTE(lds_e0);
        __syncthreads();   // drains prefetch vmcnt; e0 reads retired
        EPILOGUE(vt);
        ++vt; if (vt >= t_end) break;

        // --- round B: compute from e1, prefetch into e0 ---
        if (vt + 1 < t_end) STAGE_E(lds_e0, (vt + 1) * VT_);
        ZACC;
        COMPUTE(lds_e1);
        __syncthreads();
        EPILOGUE(vt);
        ++vt; if (vt >= t_end) break;
    }

    if (PASS == 1) {
        // reduce zs over the 32 v-columns (lane bits 0..4), once per block
#pragma unroll
        for (int msk = 1; msk < 32; msk <<= 1)
#pragma unroll
            for (int r = 0; r < 16; ++r) {
                zs0[r] += __shfl_xor(zs0[r], msk, 64);
                zs1[r] += __shfl_xor(zs1[r], msk, 64);
            }
        // each 32-lane half holds identical sums; lane (l31 == mi*16+r)
        // writes its half's m (compile-time indices only -> no scratch)
#pragma unroll
        for (int r = 0; r < 16; ++r) {
            if (l31 == r) {
                int m = m0 + wm + (r & 3) + 8 * (r >> 2) + 4 * hi;
                atomicAdd(&Z[m], zs0[r]);
            }
            if (l31 == 16 + r) {
                int m = m0 + wm + 32 + (r & 3) + 8 * (r >> 2) + 4 * hi;
                atomicAdd(&Z[m], zs1[r]);
            }
        }
    }
}

// ---------------------------------------------------------------------------
// Loss: -mean(log(clip(probs[b,label[b]], 1e-7, 1)))
// ---------------------------------------------------------------------------
__global__ __launch_bounds__(256)
void loss_kernel(const float* __restrict__ probs, const int* __restrict__ label,
                 float* __restrict__ out)
{
    __shared__ float red[256];
    int tid = threadIdx.x;
    float s = 0.f;
    for (int b = tid; b < B_; b += 256) {
        float p = probs[(size_t)b * V_ + label[b]];
        p = fminf(fmaxf(p, EPS_), 1.0f);
        s -= logf(p);
    }
    red[tid] = s;
    __syncthreads();
    for (int st = 128; st > 0; st >>= 1) {
        if (tid < st) red[tid] += red[tid + st];
        __syncthreads();
    }
    if (tid == 0) out[0] = red[0] / (float)B_;
}

// ---------------------------------------------------------------------------
extern "C" void kernel_launch(void* const* d_in, const int* in_sizes, int n_in,
                              void* d_out, int out_size, void* d_ws, size_t ws_size,
                              hipStream_t stream)
{
    const float* inputs   = (const float*)d_in[0];
    const int*   label    = (const int*)d_in[1];
    const float* emb      = (const float*)d_in[2];
    const float* proj_mat = (const float*)d_in[3];
    const float* mix_mat  = (const float*)d_in[4];
    float* out = (float*)d_out;

    char* ws = (char*)d_ws;
    ushort_t* emb_bf = (ushort_t*)ws;                       // 25,600,000 B
    ushort_t* A_bf   = (ushort_t*)(ws + 25600000);          //  1,048,576 B
    float*    pi     = (float*)(ws + 26648576);             //     16,384 B
    float*    Z      = (float*)(ws + 26664960);             //     16,384 B

    conv_kernel<<<12500, 256, 0, stream>>>(emb, emb_bf, 3200000);
    proj_pi_kernel<<<1024, 512, 0, stream>>>(inputs, proj_mat, mix_mat, A_bf, pi);
    hipMemsetAsync(Z, 0, 4096 * sizeof(float), stream);

    dim3 g(32, YB_);
    gemm_kernel<1><<<g, 256, 0, stream>>>(A_bf, emb_bf, nullptr, Z, nullptr);
    gemm_kernel<2><<<g, 256, 0, stream>>>(A_bf, emb_bf, pi, Z, out);

    loss_kernel<<<1, 256, 0, stream>>>(out, label, out + (size_t)B_ * V_);
}